// Round 9
// baseline (272.814 us; speedup 1.0000x reference)
//
#include <hip/hip_runtime.h>
#include <hip/hip_bf16.h>

#define N_NODES 50000
#define N_EDGES 250000
#define DIM 32
#define SCAN_B 1024
#define SCAN_NB ((N_NODES + SCAN_B - 1) / SCAN_B)   /* 49 */

__device__ __forceinline__ float ldf(const void* p, int i, int isf32) {
    return isf32 ? ((const float*)p)[i]
                 : __bfloat162float(((const __hip_bfloat16*)p)[i]);
}
__device__ __forceinline__ int ldi(const int* __restrict__ ei, int i, int i64) {
    return i64 ? ei[2 * i] : ei[i];
}
__device__ __forceinline__ int clamp_idx(int v) {
    v = v < 0 ? 0 : v;
    return v >= N_NODES ? N_NODES - 1 : v;
}
__device__ __forceinline__ bool half_is_big(const void* p, int k) {
    // decode 16-bit half k as bf16; fp32 buffers expose random-mantissa halves
    // that are huge/NaN with ~48% probability per even half.
    unsigned short h = ((const unsigned short*)p)[k];
    float v = __uint_as_float(((unsigned int)h) << 16);
    return !(fabsf(v) <= 50.0f);
}

// prep: per-block dtype sniff (LDS, ~6 cache lines); decode edges -> eid/eaf,
// count in-degrees; init hrA = relu(x*nW + nb). Edge part: first 977 blocks.
__global__ __launch_bounds__(256) void prep_kernel(
    const int* __restrict__ ei, const void* __restrict__ ea,
    const void* __restrict__ x, const void* __restrict__ nW,
    const void* __restrict__ nb,
    int2* __restrict__ eid, float* __restrict__ eaf,
    int* __restrict__ cntI, float* __restrict__ hrA)
{
    __shared__ int sdet;  // 1: ea f32 | 2: ei int32 | 4: x f32 | 8: nW f32 | 16: nb f32
    int tid = threadIdx.x;
    if (tid == 0) sdet = 0;
    __syncthreads();
    if (tid < 64) {
        if (ei[2 * tid + 1] != 0) atomicOr(&sdet, 2);
    } else if (tid < 128) {
        if (half_is_big(ea, tid - 64)) atomicOr(&sdet, 1);
    } else if (tid < 192) {
        if (half_is_big(x, tid - 128)) atomicOr(&sdet, 4);
    } else {
        int k = tid - 192;
        if (k < 32) { if (half_is_big(nW, k)) atomicOr(&sdet, 8); }
        else        { if (half_is_big(nb, k - 32)) atomicOr(&sdet, 16); }
    }
    __syncthreads();
    int f_ea = sdet & 1, i64 = ((sdet & 2) == 0);
    int f_x = sdet & 4, f_nW = sdet & 8, f_nb = sdet & 16;

    int g = blockIdx.x * 256 + tid;
    if (g < N_EDGES) {
        int s = clamp_idx(ldi(ei, g, i64));
        int d = clamp_idx(ldi(ei, N_EDGES + g, i64));
        eid[g] = make_int2(s, d);
        eaf[g] = ldf(ea, g, f_ea);
        atomicAdd(&cntI[d], 1);
    }
    if (g < N_NODES * DIM) {
        int n = g >> 5, d = g & 31;
        float hv = fmaf(ldf(x, n, f_x), ldf(nW, d, f_nW), ldf(nb, d, f_nb));
        hrA[g] = hv > 0.0f ? hv : 0.0f;   // relu(h0)
    }
}

// scan 1: per-block exclusive scan of cntI -> rowstart (local), block sums
__global__ __launch_bounds__(SCAN_B) void scan_local_kernel(
    const int* __restrict__ cntI, int* __restrict__ rowstart, int* __restrict__ bsum)
{
    __shared__ int b0[SCAN_B], b1[SCAN_B];
    int t = threadIdx.x;
    int g = blockIdx.x * SCAN_B + t;
    int v = (g < N_NODES) ? cntI[g] : 0;
    b0[t] = v;
    __syncthreads();
    int* src = b0; int* dst = b1;
    for (int off = 1; off < SCAN_B; off <<= 1) {
        int xv = src[t];
        if (t >= off) xv += src[t - off];
        dst[t] = xv;
        __syncthreads();
        int* tmp = src; src = dst; dst = tmp;
    }
    int incl = src[t];
    if (g < N_NODES) rowstart[g] = incl - v;
    if (t == SCAN_B - 1) bsum[blockIdx.x] = incl;
}

// scan 2: each block wave-reduces its prefix over bsum and adds it
__global__ __launch_bounds__(SCAN_B) void scan_add_kernel(
    int* __restrict__ rowstart, const int* __restrict__ bsum)
{
    __shared__ int s_prefix;
    int t = threadIdx.x, bid = blockIdx.x;
    if (t < 64) {
        int v = (t < bid && t < SCAN_NB) ? bsum[t] : 0;
        for (int off = 32; off > 0; off >>= 1) v += __shfl_down(v, off);
        if (t == 0) s_prefix = v;
    }
    __syncthreads();
    int g = bid * SCAN_B + t;
    if (g < N_NODES) rowstart[g] += s_prefix;
}

// scatter edges into CSR buckets; packed[slot] = (src, bits(a))
__global__ __launch_bounds__(256) void scatter_kernel(
    const int2* __restrict__ eid, const float* __restrict__ eaf,
    const int* __restrict__ rowstart, int* __restrict__ edge_cur,
    int2* __restrict__ packed)
{
    int e = blockIdx.x * 256 + threadIdx.x;
    if (e >= N_EDGES) return;
    int2 sd = eid[e];
    int slot = rowstart[sd.y] + atomicAdd(&edge_cur[sd.y], 1);
    packed[slot] = make_int2(sd.x, __float_as_int(eaf[e]));
}

// fused layer: P,Q = per-node edge sums over hr_in; then
// val = (P@W + Q@B)/c + hr_in[n]@root + conv_b; out = last ? val : relu(val).
// block 256 = 8 nodes x 32 lanes; weights in LDS.
__global__ __launch_bounds__(256) void layer_kernel(
    const int2* __restrict__ packed, const int* __restrict__ rowstart,
    const int* __restrict__ cntI, const float* __restrict__ hr_in,
    const void* __restrict__ l1_W, const void* __restrict__ l1_b,
    const void* __restrict__ root, const void* __restrict__ conv_b,
    float* __restrict__ outbuf, int last)
{
    __shared__ float sW[DIM * DIM], sB[DIM * DIM], sR[DIM * DIM], sCB[DIM];
    __shared__ float shP[8][DIM + 1], shQ[8][DIM + 1], shH[8][DIM + 1];
    __shared__ int sdet;  // 1: l1_W f32 | 2: l1_b f32 | 4: root f32 | 8: conv_b f32
    int tid = threadIdx.x;
    if (tid == 0) sdet = 0;
    __syncthreads();
    if (tid < 64)       { if (half_is_big(l1_W, tid)) atomicOr(&sdet, 1); }
    else if (tid < 128) { if (half_is_big(l1_b, tid - 64)) atomicOr(&sdet, 2); }
    else if (tid < 192) { if (half_is_big(root, tid - 128)) atomicOr(&sdet, 4); }
    else if (tid < 224) { if (half_is_big(conv_b, tid - 192)) atomicOr(&sdet, 8); }
    __syncthreads();
    int fW = sdet & 1, fB = sdet & 2, fR = sdet & 4, fC = sdet & 8;
    for (int k = tid; k < DIM * DIM; k += 256) {
        sW[k] = ldf(l1_W, k, fW);
        sB[k] = ldf(l1_b, k, fB);
        sR[k] = ldf(root, k, fR);
    }
    if (tid < DIM) sCB[tid] = ldf(conv_b, tid, fC);

    int local = tid >> 5, lane = tid & 31;
    int n = blockIdx.x * 8 + local;
    float p = 0.0f, q = 0.0f, hself = 0.0f;
    int deg = 0;
    if (n < N_NODES) {
        int start = rowstart[n];
        deg = cntI[n];
        for (int k = start; k < start + deg; ++k) {
            int2 sa = packed[k];                    // wave-broadcast 8B
            float a = __int_as_float(sa.y);
            float hv = hr_in[sa.x * DIM + lane];    // 128B contiguous row
            p = fmaf(a, hv, p);
            q += hv;
        }
        hself = hr_in[n * DIM + lane];
    }
    shP[local][lane] = p;
    shQ[local][lane] = q;
    shH[local][lane] = hself;
    __syncthreads();
    if (n >= N_NODES) return;

    float accP = 0.0f, accQ = 0.0f, accR = 0.0f;
    #pragma unroll
    for (int i = 0; i < DIM; ++i) {
        accP = fmaf(shP[local][i], sW[i * DIM + lane], accP);
        accQ = fmaf(shQ[local][i], sB[i * DIM + lane], accQ);
        accR = fmaf(shH[local][i], sR[i * DIM + lane], accR);
    }
    float c = deg < 1 ? 1.0f : (float)deg;
    float val = (accP + accQ) / c + accR + sCB[lane];
    outbuf[n * DIM + lane] = last ? val : (val > 0.0f ? val : 0.0f);
}

extern "C" void kernel_launch(void* const* d_in, const int* in_sizes, int n_in,
                              void* d_out, int out_size, void* d_ws, size_t ws_size,
                              hipStream_t stream) {
    // inputs by size pattern, skipping scalar args:
    // 50000(x), 500000(ei), 250000(ea), 32, 32, 1024, 1024, 1024, 32
    const void* p[16];
    int np_ = 0;
    for (int i = 0; i < n_in && np_ < 16; ++i)
        if (in_sizes[i] != 1) p[np_++] = d_in[i];

    const void* x      = p[0];
    const int*  ei     = (const int*)p[1];
    const void* ea     = p[2];
    const void* node_W = p[3];
    const void* node_b = p[4];
    const void* l1_W   = p[5];
    const void* l1_b   = p[6];
    const void* root   = p[7];
    const void* conv_b = p[8];
    float* out = (float*)d_out;

    const int ND = N_NODES * DIM;
    float* ws = (float*)d_ws;
    int2*  eid      = (int2*)ws;                    // E int2, 2 MB
    float* eaf      = (float*)(eid + N_EDGES);      // E, 1 MB
    int2*  packed   = (int2*)(eaf + N_EDGES);       // E int2, 2 MB
    float* hrA      = (float*)(packed + N_EDGES);   // N*D, 6.4 MB
    float* hrB      = hrA + ND;                     // N*D, 6.4 MB
    int*   cntI     = (int*)(hrB + ND);             // N ints (zeroed)
    int*   edge_cur = cntI + N_NODES;               // N ints (zeroed)
    int*   rowstart = edge_cur + N_NODES;           // N ints
    int*   bsum     = rowstart + N_NODES;           // 64 ints

    (void)hipMemsetAsync(cntI, 0, (size_t)(2 * N_NODES) * sizeof(int), stream);

    const int prep_blocks = (ND + 255) / 256;       // 6250 (covers 977 edge blocks)
    prep_kernel<<<prep_blocks, 256, 0, stream>>>(ei, ea, x, node_W, node_b,
                                                 eid, eaf, cntI, hrA);
    scan_local_kernel<<<SCAN_NB, SCAN_B, 0, stream>>>(cntI, rowstart, bsum);
    scan_add_kernel<<<SCAN_NB, SCAN_B, 0, stream>>>(rowstart, bsum);
    scatter_kernel<<<(N_EDGES + 255) / 256, 256, 0, stream>>>(eid, eaf, rowstart,
                                                              edge_cur, packed);

    const int node_blocks = (N_NODES + 7) / 8;      // 6250
    layer_kernel<<<node_blocks, 256, 0, stream>>>(packed, rowstart, cntI, hrA,
                                                  l1_W, l1_b, root, conv_b, hrB, 0);
    layer_kernel<<<node_blocks, 256, 0, stream>>>(packed, rowstart, cntI, hrB,
                                                  l1_W, l1_b, root, conv_b, hrA, 0);
    layer_kernel<<<node_blocks, 256, 0, stream>>>(packed, rowstart, cntI, hrA,
                                                  l1_W, l1_b, root, conv_b, out, 1);
}